// Round 1
// baseline (669.432 us; speedup 1.0000x reference)
//
#include <hip/hip_runtime.h>

// RBF kernel matvec: out[i,v] = sum_j exp(-g * max(||x_i||^2 + ||y_j||^2 - 2 x_i.y_j, 0)) * b[j,v]
// N = M = 16384, D = 32, Dv = 16, fp32.
//
// Round 0: fp32 VALU baseline. Tiled over j; y/b staged in LDS and read with
// wave-uniform (broadcast) addresses; one i-row per thread; j-split grid with
// fp32 atomics into a zeroed d_out.

#define D      32
#define DV     16
#define BJ     128     // j-tile staged in LDS
#define BLOCK  256     // threads per block = i-rows per block
#define JSPLIT 32      // j-range split across blocks (16384/32 = 512 j per block)
#define SYP    36      // padded row stride (dwords) for y tile: 16B-aligned, breaks
                       // the stride-32 bank pattern for the yn sum-of-squares pass

__global__ __launch_bounds__(BLOCK) void rbf_fp32_kernel(
    const float* __restrict__ ls,
    const float* __restrict__ x,
    const float* __restrict__ y,
    const float* __restrict__ b,
    float* __restrict__ out,
    int N, int M) {
  __shared__ float sy[BJ * SYP];
  __shared__ float sb[BJ * DV];
  __shared__ float syn[BJ];

  const int itiles = N / BLOCK;                 // 64
  const int itile  = blockIdx.x & (itiles - 1);
  const int jseg   = blockIdx.x / itiles;
  const int i      = itile * BLOCK + threadIdx.x;
  const int jlen   = M / JSPLIT;                // 512
  const int j0     = jseg * jlen;

  const float g    = ls[0];
  const float nl2g = -g * 1.4426950408889634f;  // -g * log2(e): exp(-g*sq) = exp2(nl2g*sq)

  // Load this thread's x row into registers; compute xn = ||x_i||^2.
  float xr[D];
  float xn = 0.f;
  {
    const float4* xp = (const float4*)(x + (size_t)i * D);
    #pragma unroll
    for (int q = 0; q < D / 4; ++q) {
      float4 v = xp[q];
      xr[4*q+0] = v.x; xr[4*q+1] = v.y; xr[4*q+2] = v.z; xr[4*q+3] = v.w;
      xn += v.x*v.x + v.y*v.y + v.z*v.z + v.w*v.w;
    }
  }

  float acc[DV];
  #pragma unroll
  for (int v = 0; v < DV; ++v) acc[v] = 0.f;

  for (int jt = j0; jt < j0 + jlen; jt += BJ) {
    // ---- Stage y tile (padded rows) and b tile into LDS ----
    {
      const float4* src = (const float4*)(y + (size_t)jt * D);
      #pragma unroll
      for (int r = 0; r < (BJ * D / 4) / BLOCK; ++r) {  // 4 float4 per thread
        int e4 = r * BLOCK + threadIdx.x;
        int j  = e4 >> 3;        // 8 float4 per row
        int dq = e4 & 7;
        *(float4*)&sy[j * SYP + dq * 4] = src[e4];
      }
      const float4* bsrc = (const float4*)(b + (size_t)jt * DV);
      #pragma unroll
      for (int r = 0; r < (BJ * DV / 4) / BLOCK; ++r) { // 2 float4 per thread
        int e4 = r * BLOCK + threadIdx.x;
        *(float4*)&sb[e4 * 4] = bsrc[e4];
      }
    }
    __syncthreads();

    // ---- yn for this tile (threads 0..BJ-1), once per tile ----
    if (threadIdx.x < BJ) {
      const float* row = &sy[threadIdx.x * SYP];
      float s0 = 0.f, s1 = 0.f, s2 = 0.f, s3 = 0.f;
      #pragma unroll
      for (int d = 0; d < D; d += 4) {
        s0 = fmaf(row[d+0], row[d+0], s0);
        s1 = fmaf(row[d+1], row[d+1], s1);
        s2 = fmaf(row[d+2], row[d+2], s2);
        s3 = fmaf(row[d+3], row[d+3], s3);
      }
      syn[threadIdx.x] = (s0 + s1) + (s2 + s3);
    }
    __syncthreads();

    // ---- Main loop: all LDS reads are wave-uniform broadcasts ----
    #pragma unroll 2
    for (int j = 0; j < BJ; ++j) {
      const float* yrow = &sy[j * SYP];
      float d0 = 0.f, d1 = 0.f, d2 = 0.f, d3 = 0.f;
      #pragma unroll
      for (int d = 0; d < D; d += 4) {
        d0 = fmaf(xr[d+0], yrow[d+0], d0);
        d1 = fmaf(xr[d+1], yrow[d+1], d1);
        d2 = fmaf(xr[d+2], yrow[d+2], d2);
        d3 = fmaf(xr[d+3], yrow[d+3], d3);
      }
      float dot = (d0 + d1) + (d2 + d3);
      float sq  = fmaxf(xn + syn[j] - 2.0f * dot, 0.0f);
      float p   = exp2f(nl2g * sq);   // -> v_exp_f32
      const float* brow = &sb[j * DV];
      #pragma unroll
      for (int v = 0; v < DV; ++v) acc[v] = fmaf(p, brow[v], acc[v]);
    }
    __syncthreads();
  }

  // ---- Accumulate partial results (JSPLIT blocks per i) ----
  float* orow = out + (size_t)i * DV;
  #pragma unroll
  for (int v = 0; v < DV; ++v) atomicAdd(&orow[v], acc[v]);
}

extern "C" void kernel_launch(void* const* d_in, const int* in_sizes, int n_in,
                              void* d_out, int out_size, void* d_ws, size_t ws_size,
                              hipStream_t stream) {
  const float* ls = (const float*)d_in[0];
  const float* x  = (const float*)d_in[1];
  const float* y  = (const float*)d_in[2];
  const float* b  = (const float*)d_in[3];
  float* out = (float*)d_out;

  const int N = in_sizes[1] / D;   // 16384
  const int M = in_sizes[2] / D;   // 16384

  // d_out is poisoned (0xAA) before every launch; atomics need zeros.
  hipMemsetAsync(d_out, 0, (size_t)out_size * sizeof(float), stream);

  const int itiles = N / BLOCK;            // 64
  dim3 grid(itiles * JSPLIT);              // 2048 blocks
  rbf_fp32_kernel<<<grid, BLOCK, 0, stream>>>(ls, x, y, b, out, N, M);
}

// Round 3
// 383.291 us; speedup vs baseline: 1.7465x; 1.7465x over previous
//
#include <hip/hip_runtime.h>

// out[i,v] = sum_j exp(-g*max(xn_i + yn_j - 2 x_i.y_j, 0)) * b[j,v]
// N=M=16384, D=32, Dv=16, fp32.
//
// Round 3: same as round 2 (MFMA 16x16x32 f16 flash-style), fixing the
// cvt_pkrtz return-type mismatch (__fp16 vec2, not _Float16 vec2).

#define NPTS 16384
#define D    32
#define DV   16
#define JSPLIT 8
#define JBLK 64
#define IBLK 64           // 4 waves x 16 rows
#define PTS  72           // halves per i-row in LDS P buffer (pad vs 64)

typedef _Float16 half8  __attribute__((ext_vector_type(8)));
typedef _Float16 half4_t __attribute__((ext_vector_type(4)));
typedef __fp16   cvt2_t  __attribute__((ext_vector_type(2)));  // cvt_pkrtz return type
typedef float    float4_t __attribute__((ext_vector_type(4)));

// ---------------- prologue: yn, y_hi/lo, bT_hi/lo ----------------
__global__ __launch_bounds__(256) void rbf_prologue(
    const float* __restrict__ y, const float* __restrict__ b,
    float* __restrict__ yn, _Float16* __restrict__ yh, _Float16* __restrict__ yl,
    _Float16* __restrict__ bTh, _Float16* __restrict__ bTl) {
  const int j = blockIdx.x * 256 + threadIdx.x;
  const float4_t* yr = (const float4_t*)(y + (size_t)j * D);
  half8 h8[4], l8[4];
  float s = 0.f;
  #pragma unroll
  for (int c = 0; c < 4; ++c) {
    float4_t a = yr[2*c], bb = yr[2*c+1];
    float f[8] = {a[0],a[1],a[2],a[3],bb[0],bb[1],bb[2],bb[3]};
    #pragma unroll
    for (int k = 0; k < 8; ++k) {
      s = fmaf(f[k], f[k], s);
      _Float16 h = (_Float16)f[k];
      h8[c][k] = h;
      l8[c][k] = (_Float16)(f[k] - (float)h);
    }
  }
  yn[j] = s;
  half8* yhp = (half8*)(yh + (size_t)j * D);
  half8* ylp = (half8*)(yl + (size_t)j * D);
  #pragma unroll
  for (int c = 0; c < 4; ++c) { yhp[c] = h8[c]; ylp[c] = l8[c]; }

  const float4_t* br = (const float4_t*)(b + (size_t)j * DV);
  #pragma unroll
  for (int c = 0; c < 4; ++c) {
    float4_t v = br[c];
    #pragma unroll
    for (int k = 0; k < 4; ++k) {
      int vv = c*4 + k;
      _Float16 h = (_Float16)v[k];
      bTh[(size_t)vv * NPTS + j] = h;                      // coalesced over j
      bTl[(size_t)vv * NPTS + j] = (_Float16)(v[k] - (float)h);
    }
  }
}

// ---------------- main MFMA kernel ----------------
__global__ __launch_bounds__(256) void rbf_mfma(
    const float* __restrict__ ls, const float* __restrict__ x,
    const float* __restrict__ yn, const _Float16* __restrict__ yh,
    const _Float16* __restrict__ yl, const _Float16* __restrict__ bTh,
    const _Float16* __restrict__ bTl, float* __restrict__ out) {
  __shared__ _Float16 PBUF[4][16 * PTS];   // per-wave private P tile, no barriers

  const int iblk = blockIdx.x & 255;       // N/IBLK = 256
  const int jseg = blockIdx.x >> 8;
  const int lane = threadIdx.x & 63;
  const int wv   = threadIdx.x >> 6;
  const int t    = lane & 15;
  const int q    = lane >> 4;

  const int ibase = iblk * IBLK + wv * 16;
  const int jlen  = NPTS / JSPLIT;         // 2048
  const int j0    = jseg * jlen;

  const float g    = ls[0];
  const float nl2g = -g * 1.4426950408889634f;

  // x fragment: B-operand of S^T = (-2x)[i=ibase+t][d=q*8..q*8+7], fp16 hi/lo.
  // xn = full ||x_i||^2 via cross-quad shuffle reduce.
  half8 xh, xl;
  float xn;
  {
    const float4_t* xp = (const float4_t*)(x + (size_t)(ibase + t) * D + q * 8);
    float4_t a0 = xp[0], a1 = xp[1];
    float f[8] = {a0[0],a0[1],a0[2],a0[3],a1[0],a1[1],a1[2],a1[3]};
    float s = 0.f;
    #pragma unroll
    for (int k = 0; k < 8; ++k) {
      s = fmaf(f[k], f[k], s);
      float v = -2.0f * f[k];
      _Float16 h = (_Float16)v;
      xh[k] = h;
      xl[k] = (_Float16)(v - (float)h);
    }
    s += __shfl_xor(s, 16);
    s += __shfl_xor(s, 32);
    xn = s;
  }

  float4_t acc0 = {0.f,0.f,0.f,0.f};       // out^T tile, 2 chains for ILP
  float4_t acc1 = {0.f,0.f,0.f,0.f};
  _Float16* myP = &PBUF[wv][0];

  for (int jb = j0; jb < j0 + jlen; jb += JBLK) {
    // ---- 4 subtiles: S^T = xn+yn-2*x.y via 3 MFMAs, exp2, pack, LDS write ----
    #pragma unroll
    for (int s = 0; s < 4; ++s) {
      const int jrow = jb + s * 16 + t;    // A-operand row (j) for this lane
      const half8 ah = *(const half8*)(yh + (size_t)jrow * D + q * 8);
      const half8 al = *(const half8*)(yl + (size_t)jrow * D + q * 8);
      const float4_t yn4 = *(const float4_t*)(yn + jb + s * 16 + q * 4);
      float4_t c = {yn4[0] + xn, yn4[1] + xn, yn4[2] + xn, yn4[3] + xn};
      c = __builtin_amdgcn_mfma_f32_16x16x32_f16(ah, xh, c, 0, 0, 0);
      c = __builtin_amdgcn_mfma_f32_16x16x32_f16(ah, xl, c, 0, 0, 0);
      c = __builtin_amdgcn_mfma_f32_16x16x32_f16(al, xh, c, 0, 0, 0);
      // p' = 2^14 * exp2(nl2g * max(sq,0))  (scale keeps p' in fp16 normal range)
      float p0 = exp2f(fmaf(nl2g, fmaxf(c[0], 0.f), 14.0f));
      float p1 = exp2f(fmaf(nl2g, fmaxf(c[1], 0.f), 14.0f));
      float p2 = exp2f(fmaf(nl2g, fmaxf(c[2], 0.f), 14.0f));
      float p3 = exp2f(fmaf(nl2g, fmaxf(c[3], 0.f), 14.0f));
      union { half4_t h4; cvt2_t c2[2]; } u;
      u.c2[0] = __builtin_amdgcn_cvt_pkrtz(p0, p1);
      u.c2[1] = __builtin_amdgcn_cvt_pkrtz(p2, p3);
      // P[i=t][j_local = s*16 + q*4 .. +3]
      *(half4_t*)&myP[t * PTS + s * 16 + q * 4] = u.h4;
    }
    // Same-wave RAW through LDS: DS ops are in-order per wave; this stops the
    // compiler from sinking the reads above the writes:
    __asm__ volatile("s_waitcnt lgkmcnt(0)" ::: "memory");

    // ---- out^T += bT x P : A=bT[v][j] (2-split), B=P[i][j] read as B^T rows ----
    #pragma unroll
    for (int cc = 0; cc < 2; ++cc) {
      const half8 pt = *(const half8*)&myP[t * PTS + cc * 32 + q * 8];
      const half8 bh = *(const half8*)(bTh + (size_t)t * NPTS + jb + cc * 32 + q * 8);
      const half8 bl = *(const half8*)(bTl + (size_t)t * NPTS + jb + cc * 32 + q * 8);
      acc0 = __builtin_amdgcn_mfma_f32_16x16x32_f16(bh, pt, acc0, 0, 0, 0);
      acc1 = __builtin_amdgcn_mfma_f32_16x16x32_f16(bl, pt, acc1, 0, 0, 0);
    }
  }

  // ---- epilogue: acc holds out^T[v=q*4+reg][i=ibase+t] * 2^14 ----
  const float sc = 0.00006103515625f;      // 2^-14
  float* orow = out + (size_t)(ibase + t) * DV + q * 4;
  #pragma unroll
  for (int r = 0; r < 4; ++r) atomicAdd(&orow[r], (acc0[r] + acc1[r]) * sc);
}

// ---------------- fallback (round-0 fp32 kernel, no ws) ----------------
#define BJ     128
#define BLOCK  256
#define FJSPLIT 32
#define SYP    36

__global__ __launch_bounds__(BLOCK) void rbf_fp32_kernel(
    const float* __restrict__ ls, const float* __restrict__ x,
    const float* __restrict__ y, const float* __restrict__ b,
    float* __restrict__ out, int N, int M) {
  __shared__ float sy[BJ * SYP];
  __shared__ float sb[BJ * DV];
  __shared__ float syn[BJ];
  const int itiles = N / BLOCK;
  const int itile  = blockIdx.x & (itiles - 1);
  const int jseg   = blockIdx.x / itiles;
  const int i      = itile * BLOCK + threadIdx.x;
  const int jlen   = M / FJSPLIT;
  const int j0     = jseg * jlen;
  const float g    = ls[0];
  const float nl2g = -g * 1.4426950408889634f;
  float xr[D]; float xn = 0.f;
  {
    const float4* xp = (const float4*)(x + (size_t)i * D);
    #pragma unroll
    for (int qq = 0; qq < D / 4; ++qq) {
      float4 v = xp[qq];
      xr[4*qq+0]=v.x; xr[4*qq+1]=v.y; xr[4*qq+2]=v.z; xr[4*qq+3]=v.w;
      xn += v.x*v.x + v.y*v.y + v.z*v.z + v.w*v.w;
    }
  }
  float acc[DV];
  #pragma unroll
  for (int v = 0; v < DV; ++v) acc[v] = 0.f;
  for (int jt = j0; jt < j0 + jlen; jt += BJ) {
    {
      const float4* src = (const float4*)(y + (size_t)jt * D);
      #pragma unroll
      for (int r = 0; r < (BJ * D / 4) / BLOCK; ++r) {
        int e4 = r * BLOCK + threadIdx.x;
        int j  = e4 >> 3; int dq = e4 & 7;
        *(float4*)&sy[j * SYP + dq * 4] = src[e4];
      }
      const float4* bsrc = (const float4*)(b + (size_t)jt * DV);
      #pragma unroll
      for (int r = 0; r < (BJ * DV / 4) / BLOCK; ++r) {
        int e4 = r * BLOCK + threadIdx.x;
        *(float4*)&sb[e4 * 4] = bsrc[e4];
      }
    }
    __syncthreads();
    if (threadIdx.x < BJ) {
      const float* row = &sy[threadIdx.x * SYP];
      float s0=0,s1=0,s2=0,s3=0;
      #pragma unroll
      for (int d = 0; d < D; d += 4) {
        s0=fmaf(row[d+0],row[d+0],s0); s1=fmaf(row[d+1],row[d+1],s1);
        s2=fmaf(row[d+2],row[d+2],s2); s3=fmaf(row[d+3],row[d+3],s3);
      }
      syn[threadIdx.x] = (s0+s1)+(s2+s3);
    }
    __syncthreads();
    #pragma unroll 2
    for (int j = 0; j < BJ; ++j) {
      const float* yrow = &sy[j * SYP];
      float d0=0,d1=0,d2=0,d3=0;
      #pragma unroll
      for (int d = 0; d < D; d += 4) {
        d0=fmaf(xr[d+0],yrow[d+0],d0); d1=fmaf(xr[d+1],yrow[d+1],d1);
        d2=fmaf(xr[d+2],yrow[d+2],d2); d3=fmaf(xr[d+3],yrow[d+3],d3);
      }
      float dot=(d0+d1)+(d2+d3);
      float sq = fmaxf(xn + syn[j] - 2.0f*dot, 0.0f);
      float p  = exp2f(nl2g * sq);
      const float* brow = &sb[j * DV];
      #pragma unroll
      for (int v = 0; v < DV; ++v) acc[v] = fmaf(p, brow[v], acc[v]);
    }
    __syncthreads();
  }
  float* orow = out + (size_t)i * DV;
  #pragma unroll
  for (int v = 0; v < DV; ++v) atomicAdd(&orow[v], acc[v]);
}

extern "C" void kernel_launch(void* const* d_in, const int* in_sizes, int n_in,
                              void* d_out, int out_size, void* d_ws, size_t ws_size,
                              hipStream_t stream) {
  const float* ls = (const float*)d_in[0];
  const float* x  = (const float*)d_in[1];
  const float* y  = (const float*)d_in[2];
  const float* b  = (const float*)d_in[3];
  float* out = (float*)d_out;

  (void)hipMemsetAsync(d_out, 0, (size_t)out_size * sizeof(float), stream);

  // ws carve: yn (64KB) | y_hi (1MB) | y_lo (1MB) | bT_hi (512KB) | bT_lo (512KB)
  const size_t yn_b  = (size_t)NPTS * 4;
  const size_t yhl_b = (size_t)NPTS * D * 2;
  const size_t bT_b  = (size_t)DV * NPTS * 2;
  const size_t need  = yn_b + 2 * yhl_b + 2 * bT_b;   // ~3.1 MB

  if (ws_size >= need) {
    char* w = (char*)d_ws;
    float*    yn  = (float*)w;                 w += yn_b;
    _Float16* yhp = (_Float16*)w;              w += yhl_b;
    _Float16* ylp = (_Float16*)w;              w += yhl_b;
    _Float16* bTh = (_Float16*)w;              w += bT_b;
    _Float16* bTl = (_Float16*)w;
    rbf_prologue<<<NPTS / 256, 256, 0, stream>>>(y, b, yn, yhp, ylp, bTh, bTl);
    dim3 grid((NPTS / IBLK) * JSPLIT);         // 256 * 8 = 2048
    rbf_mfma<<<grid, 256, 0, stream>>>(ls, x, yn, yhp, ylp, bTh, bTl, out);
  } else {
    dim3 grid((NPTS / BLOCK) * FJSPLIT);
    rbf_fp32_kernel<<<grid, BLOCK, 0, stream>>>(ls, x, y, b, out, NPTS, NPTS);
  }
}

// Round 4
// 189.160 us; speedup vs baseline: 3.5390x; 2.0263x over previous
//
#include <hip/hip_runtime.h>

// out[i,v] = sum_j exp(-g*max(xn_i + yn_j - 2 x_i.y_j, 0)) * b[j,v]
// N=M=16384, D=32, Dv=16, fp32.
//
// Round 4: block-staged LDS tiles via global_load_lds (double-buffered),
// IBLK=128 (2 i-frags/wave), bT single-fp16, yl from global (prefetched).
// Record per j-tile (64 j): [yn 256B | yh 64x40h (80B rows) | bTh 16x72h] = 7680B.

#define NPTS 16384
#define D    32
#define DV   16
#define IBLK 128
#define JSPLIT 8
#define JBLK 64
#define NTILE  (NPTS / JBLK)        // 256
#define TILES  (NTILE / JSPLIT)     // 32 per block
#define REC    7680
#define YH_OFF 256                  // yh rows: stride 80 B (40 halves)
#define BT_OFF 5376                 // bTh rows: stride 144 B (72 halves)
#define PTS    72

typedef _Float16 half8   __attribute__((ext_vector_type(8)));
typedef _Float16 half4_t __attribute__((ext_vector_type(4)));
typedef __fp16   cvt2_t  __attribute__((ext_vector_type(2)));
typedef float    float4_t __attribute__((ext_vector_type(4)));
typedef unsigned int u32;

__device__ __forceinline__ void async16(const void* g, void* l) {
  __builtin_amdgcn_global_load_lds((const __attribute__((address_space(1))) u32*)g,
                                   (__attribute__((address_space(3))) u32*)l, 16, 0, 0);
}

__device__ __forceinline__ void stage_tile(const char* __restrict__ g,
                                           char* __restrict__ l, int tid) {
  async16(g + tid * 16, l + tid * 16);                       // [0,4096)
  if (tid < 224) async16(g + 4096 + tid * 16, l + 4096 + tid * 16);  // [4096,7680)
}

// ---------------- prologue: build tile records + yl ----------------
__global__ __launch_bounds__(256) void rbf_prologue(
    const float* __restrict__ y, const float* __restrict__ b,
    char* __restrict__ rec0, _Float16* __restrict__ ylg) {
  __shared__ _Float16 sb[256][17];
  const int tid = threadIdx.x;
  const int j = blockIdx.x * 256 + tid;
  const int tt = j >> 6, jloc = j & 63;
  char* rec = rec0 + (size_t)tt * REC;

  // y row: yn + hi/lo split
  const float4* yp = (const float4*)(y + (size_t)j * D);
  float s = 0.f;
  _Float16 hi[32], lo[32];
  #pragma unroll
  for (int c = 0; c < 8; ++c) {
    float4 v = yp[c];
    float f[4] = {v.x, v.y, v.z, v.w};
    #pragma unroll
    for (int k = 0; k < 4; ++k) {
      s = fmaf(f[k], f[k], s);
      _Float16 h = (_Float16)f[k];
      hi[c*4+k] = h;
      lo[c*4+k] = (_Float16)(f[k] - (float)h);
    }
  }
  ((float*)rec)[jloc] = s;
  #pragma unroll
  for (int c = 0; c < 4; ++c) {
    *(half8*)(rec + YH_OFF + jloc * 80 + c * 16) = *(half8*)&hi[c*8];
    *(half8*)(ylg + (size_t)j * D + c * 8)       = *(half8*)&lo[c*8];
  }

  // b: LDS transpose -> bTh[v][jloc] rows (stride 72 halves) in records
  const float4* bp = (const float4*)(b + (size_t)j * DV);
  #pragma unroll
  for (int c = 0; c < 4; ++c) {
    float4 v = bp[c];
    sb[tid][c*4+0] = (_Float16)v.x; sb[tid][c*4+1] = (_Float16)v.y;
    sb[tid][c*4+2] = (_Float16)v.z; sb[tid][c*4+3] = (_Float16)v.w;
  }
  __syncthreads();
  #pragma unroll
  for (int r = 0; r < 2; ++r) {
    int cch = r * 256 + tid;                 // 512 chunks of 16B (4 tiles)
    int t4 = cch >> 7, rem = cch & 127, v = rem >> 3, jg = rem & 7;
    _Float16 tmp[8];
    #pragma unroll
    for (int k = 0; k < 8; ++k) tmp[k] = sb[t4*64 + jg*8 + k][v];
    *(half8*)(rec0 + (size_t)(blockIdx.x*4 + t4)*REC + BT_OFF + v*144 + jg*16) =
        *(half8*)tmp;
  }
}

// ---------------- main MFMA kernel ----------------
__global__ __launch_bounds__(256, 4) void rbf_mfma(
    const float* __restrict__ ls, const float* __restrict__ x,
    const char* __restrict__ rec0, const _Float16* __restrict__ ylg,
    float* __restrict__ out) {
  __shared__ __align__(16) char SB[2][REC];           // 15360 B
  __shared__ __align__(16) _Float16 P[4][2][16 * PTS]; // 18432 B

  const int tid  = threadIdx.x;
  const int lane = tid & 63, w = tid >> 6;
  const int t = lane & 15, q = lane >> 4;
  const int iblk = blockIdx.x & 127, jseg = blockIdx.x >> 7;
  const int tseg = jseg * TILES;

  const float g    = ls[0];
  const float nl2g = -g * 1.4426950408889634f;

  // x fragments (2 per wave), -2x folded, hi/lo split; xn via shuffle reduce
  half8 xh[2], xl[2];
  float xn[2];
  #pragma unroll
  for (int f = 0; f < 2; ++f) {
    const int row = iblk * IBLK + f * 64 + w * 16 + t;
    const float4* xp = (const float4*)(x + (size_t)row * D + q * 8);
    float4 a0 = xp[0], a1 = xp[1];
    float fv[8] = {a0.x,a0.y,a0.z,a0.w,a1.x,a1.y,a1.z,a1.w};
    float s = 0.f;
    #pragma unroll
    for (int k = 0; k < 8; ++k) {
      s = fmaf(fv[k], fv[k], s);
      float vv = -2.0f * fv[k];
      _Float16 h = (_Float16)vv;
      xh[f][k] = h;
      xl[f][k] = (_Float16)(vv - (float)h);
    }
    s += __shfl_xor(s, 16);
    s += __shfl_xor(s, 32);
    xn[f] = s;
  }

  float4_t acc[2] = {{0.f,0.f,0.f,0.f},{0.f,0.f,0.f,0.f}};
  _Float16* __restrict__ P0 = &P[w][0][0];
  _Float16* __restrict__ P1 = &P[w][1][0];

  stage_tile(rec0 + (size_t)tseg * REC, &SB[0][0], tid);
  __syncthreads();

  const _Float16* ylbase = ylg + (size_t)tseg * JBLK * D + (size_t)t * D + q * 8;

  for (int k = 0; k < TILES; ++k) {
    // prefetch this tile's yl fragments from global (L2)
    half8 alp[4];
    const _Float16* ylrow = ylbase + (size_t)k * JBLK * D;
    #pragma unroll
    for (int s = 0; s < 4; ++s) alp[s] = *(const half8*)(ylrow + s * 16 * D);

    // async-stage next tile
    if (k + 1 < TILES)
      stage_tile(rec0 + (size_t)(tseg + k + 1) * REC, &SB[(k + 1) & 1][0], tid);

    const char* rec = &SB[k & 1][0];
    const float* ynp = (const float*)rec;
    const char* yhp = rec + YH_OFF;
    const _Float16* btp = (const _Float16*)(rec + BT_OFF);

    // ---- S^T tiles: 3-MFMA split, exp2, pack to per-wave P ----
    #pragma unroll
    for (int s = 0; s < 4; ++s) {
      const half8 ah = *(const half8*)(yhp + (s * 16 + t) * 80 + q * 16);
      const float4_t yn4 = *(const float4_t*)(ynp + s * 16 + q * 4);
      #pragma unroll
      for (int f = 0; f < 2; ++f) {
        float4_t c = {yn4[0] + xn[f], yn4[1] + xn[f], yn4[2] + xn[f], yn4[3] + xn[f]};
        c = __builtin_amdgcn_mfma_f32_16x16x32_f16(ah, xh[f], c, 0, 0, 0);
        c = __builtin_amdgcn_mfma_f32_16x16x32_f16(ah, xl[f], c, 0, 0, 0);
        c = __builtin_amdgcn_mfma_f32_16x16x32_f16(alp[s], xh[f], c, 0, 0, 0);
        float p0 = exp2f(fmaf(nl2g, fmaxf(c[0], 0.f), 14.0f));
        float p1 = exp2f(fmaf(nl2g, fmaxf(c[1], 0.f), 14.0f));
        float p2 = exp2f(fmaf(nl2g, fmaxf(c[2], 0.f), 14.0f));
        float p3 = exp2f(fmaf(nl2g, fmaxf(c[3], 0.f), 14.0f));
        union { half4_t h4; cvt2_t c2[2]; } u;
        u.c2[0] = __builtin_amdgcn_cvt_pkrtz(p0, p1);
        u.c2[1] = __builtin_amdgcn_cvt_pkrtz(p2, p3);
        _Float16* dst = (f == 0) ? P0 : P1;
        *(half4_t*)&dst[t * PTS + s * 16 + q * 4] = u.h4;
      }
    }
    // order P writes before P reads (DS only; does NOT drain async staging)
    __asm__ volatile("s_waitcnt lgkmcnt(0)" ::: "memory");

    // ---- out^T += bT x P ----
    #pragma unroll
    for (int cc = 0; cc < 2; ++cc) {
      const half8 bh  = *(const half8*)(btp + t * PTS + cc * 32 + q * 8);
      const half8 pt0 = *(const half8*)&P0[t * PTS + cc * 32 + q * 8];
      const half8 pt1 = *(const half8*)&P1[t * PTS + cc * 32 + q * 8];
      acc[0] = __builtin_amdgcn_mfma_f32_16x16x32_f16(bh, pt0, acc[0], 0, 0, 0);
      acc[1] = __builtin_amdgcn_mfma_f32_16x16x32_f16(bh, pt1, acc[1], 0, 0, 0);
    }
    __syncthreads();   // drains staging vmcnt; protects both LDS buffers
  }

  const float sc = 0.00006103515625f;  // 2^-14
  #pragma unroll
  for (int f = 0; f < 2; ++f) {
    float* orow = out + (size_t)(iblk * IBLK + f * 64 + w * 16 + t) * DV + q * 4;
    #pragma unroll
    for (int r = 0; r < 4; ++r) atomicAdd(&orow[r], acc[f][r] * sc);
  }
}

// ---------------- fallback (round-0 fp32 kernel, no ws) ----------------
#define BJ     128
#define BLOCK  256
#define FJSPLIT 32
#define SYP    36

__global__ __launch_bounds__(BLOCK) void rbf_fp32_kernel(
    const float* __restrict__ ls, const float* __restrict__ x,
    const float* __restrict__ y, const float* __restrict__ b,
    float* __restrict__ out, int N, int M) {
  __shared__ float sy[BJ * SYP];
  __shared__ float sb[BJ * DV];
  __shared__ float syn[BJ];
  const int itiles = N / BLOCK;
  const int itile  = blockIdx.x & (itiles - 1);
  const int jseg   = blockIdx.x / itiles;
  const int i      = itile * BLOCK + threadIdx.x;
  const int jlen   = M / FJSPLIT;
  const int j0     = jseg * jlen;
  const float g    = ls[0];
  const float nl2g = -g * 1.4426950408889634f;
  float xr[D]; float xn = 0.f;
  {
    const float4* xp = (const float4*)(x + (size_t)i * D);
    #pragma unroll
    for (int qq = 0; qq < D / 4; ++qq) {
      float4 v = xp[qq];
      xr[4*qq+0]=v.x; xr[4*qq+1]=v.y; xr[4*qq+2]=v.z; xr[4*qq+3]=v.w;
      xn += v.x*v.x + v.y*v.y + v.z*v.z + v.w*v.w;
    }
  }
  float acc[DV];
  #pragma unroll
  for (int v = 0; v < DV; ++v) acc[v] = 0.f;
  for (int jt = j0; jt < j0 + jlen; jt += BJ) {
    {
      const float4* src = (const float4*)(y + (size_t)jt * D);
      #pragma unroll
      for (int r = 0; r < (BJ * D / 4) / BLOCK; ++r) {
        int e4 = r * BLOCK + threadIdx.x;
        int j  = e4 >> 3; int dq = e4 & 7;
        *(float4*)&sy[j * SYP + dq * 4] = src[e4];
      }
      const float4* bsrc = (const float4*)(b + (size_t)jt * DV);
      #pragma unroll
      for (int r = 0; r < (BJ * DV / 4) / BLOCK; ++r) {
        int e4 = r * BLOCK + threadIdx.x;
        *(float4*)&sb[e4 * 4] = bsrc[e4];
      }
    }
    __syncthreads();
    if (threadIdx.x < BJ) {
      const float* row = &sy[threadIdx.x * SYP];
      float s0=0,s1=0,s2=0,s3=0;
      #pragma unroll
      for (int d = 0; d < D; d += 4) {
        s0=fmaf(row[d+0],row[d+0],s0); s1=fmaf(row[d+1],row[d+1],s1);
        s2=fmaf(row[d+2],row[d+2],s2); s3=fmaf(row[d+3],row[d+3],s3);
      }
      syn[threadIdx.x] = (s0+s1)+(s2+s3);
    }
    __syncthreads();
    #pragma unroll 2
    for (int j = 0; j < BJ; ++j) {
      const float* yrow = &sy[j * SYP];
      float d0=0,d1=0,d2=0,d3=0;
      #pragma unroll
      for (int d = 0; d < D; d += 4) {
        d0=fmaf(xr[d+0],yrow[d+0],d0); d1=fmaf(xr[d+1],yrow[d+1],d1);
        d2=fmaf(xr[d+2],yrow[d+2],d2); d3=fmaf(xr[d+3],yrow[d+3],d3);
      }
      float dot=(d0+d1)+(d2+d3);
      float sq = fmaxf(xn + syn[j] - 2.0f*dot, 0.0f);
      float p  = exp2f(nl2g * sq);
      const float* brow = &sb[j * DV];
      #pragma unroll
      for (int v = 0; v < DV; ++v) acc[v] = fmaf(p, brow[v], acc[v]);
    }
    __syncthreads();
  }
  float* orow = out + (size_t)i * DV;
  #pragma unroll
  for (int v = 0; v < DV; ++v) atomicAdd(&orow[v], acc[v]);
}

extern "C" void kernel_launch(void* const* d_in, const int* in_sizes, int n_in,
                              void* d_out, int out_size, void* d_ws, size_t ws_size,
                              hipStream_t stream) {
  const float* ls = (const float*)d_in[0];
  const float* x  = (const float*)d_in[1];
  const float* y  = (const float*)d_in[2];
  const float* b  = (const float*)d_in[3];
  float* out = (float*)d_out;

  (void)hipMemsetAsync(d_out, 0, (size_t)out_size * sizeof(float), stream);

  const size_t rec_b = (size_t)NTILE * REC;        // 1,966,080
  const size_t yl_b  = (size_t)NPTS * D * 2;       // 1,048,576
  const size_t need  = rec_b + yl_b;               // ~3.0 MB

  if (ws_size >= need) {
    char* w = (char*)d_ws;
    char*     rec0 = w;
    _Float16* ylg  = (_Float16*)(w + rec_b);
    rbf_prologue<<<NPTS / 256, 256, 0, stream>>>(y, b, rec0, ylg);
    dim3 grid((NPTS / IBLK) * JSPLIT);             // 128 * 8 = 1024
    rbf_mfma<<<grid, 256, 0, stream>>>(ls, x, rec0, ylg, out);
  } else {
    dim3 grid((NPTS / BLOCK) * FJSPLIT);
    rbf_fp32_kernel<<<grid, BLOCK, 0, stream>>>(ls, x, y, b, out, NPTS, NPTS);
  }
}

// Round 5
// 184.023 us; speedup vs baseline: 3.6378x; 1.0279x over previous
//
#include <hip/hip_runtime.h>

// out[i,v] = sum_j exp(-g*max(xn_i + yn_j - 2 x_i.y_j, 0)) * b[j,v]
// N=M=16384, D=32, Dv=16, fp32.
//
// Round 5: fold nl2g=-g*log2e into MFMA inputs (x side scaled by -2*nl2g,
// yn pre-scaled, +14 fp16-denorm-guard folded into xn') so per element the
// epilogue is add+exp2+halfpack. IBLK=256 (4 frags/wave), yl staged in the
// record (no global loads in loop), single per-wave P buffer, memset fused
// into prologue. Record per 64-j tile:
//   [yn' 256B | yh 64x80B | yl 64x80B | bTh 16x144B] = 12800 B.

#define NPTS 16384
#define D    32
#define DV   16
#define IBLK 256
#define JSPLIT 16
#define JBLK 64
#define NTILE  (NPTS / JBLK)        // 256
#define TILES  (NTILE / JSPLIT)     // 16 per block
#define REC    12800
#define YH_OFF 256
#define YL_OFF 5376
#define BT_OFF 10496
#define PTS    72                   // P row stride in halves

typedef _Float16 half8   __attribute__((ext_vector_type(8)));
typedef _Float16 half4_t __attribute__((ext_vector_type(4)));
typedef __fp16   cvt2_t  __attribute__((ext_vector_type(2)));
typedef float    float4_t __attribute__((ext_vector_type(4)));
typedef unsigned int u32;

__device__ __forceinline__ void async16(const void* g, void* l) {
  __builtin_amdgcn_global_load_lds((const __attribute__((address_space(1))) u32*)g,
                                   (__attribute__((address_space(3))) u32*)l, 16, 0, 0);
}

__device__ __forceinline__ void stage_tile(const char* __restrict__ g,
                                           char* __restrict__ l, int tid) {
  async16(g + tid * 16,         l + tid * 16);
  async16(g + 4096 + tid * 16,  l + 4096 + tid * 16);
  async16(g + 8192 + tid * 16,  l + 8192 + tid * 16);
  if (tid < 32) async16(g + 12288 + tid * 16, l + 12288 + tid * 16);
}

// ---------------- prologue: records (yn' scaled, yh, yl, bTh) + out zero ----
__global__ __launch_bounds__(256) void rbf_prologue(
    const float* __restrict__ ls, const float* __restrict__ y,
    const float* __restrict__ b, char* __restrict__ rec0,
    float* __restrict__ outz) {
  __shared__ _Float16 sbt[256][17];
  const int tid = threadIdx.x;
  const int j = blockIdx.x * 256 + tid;
  const int tt = j >> 6, jloc = j & 63;
  char* rec = rec0 + (size_t)tt * REC;
  const float nl2g = -ls[0] * 1.4426950408889634f;

  // y row: scaled yn' + plain hi/lo split
  const float4* yp = (const float4*)(y + (size_t)j * D);
  float s = 0.f;
  _Float16 hi[32], lo[32];
  #pragma unroll
  for (int c = 0; c < 8; ++c) {
    float4 v = yp[c];
    float f[4] = {v.x, v.y, v.z, v.w};
    #pragma unroll
    for (int k = 0; k < 4; ++k) {
      s = fmaf(f[k], f[k], s);
      _Float16 h = (_Float16)f[k];
      hi[c*4+k] = h;
      lo[c*4+k] = (_Float16)(f[k] - (float)h);
    }
  }
  ((float*)rec)[jloc] = nl2g * s;
  #pragma unroll
  for (int c = 0; c < 4; ++c) {
    *(half8*)(rec + YH_OFF + jloc * 80 + c * 16) = *(half8*)&hi[c*8];
    *(half8*)(rec + YL_OFF + jloc * 80 + c * 16) = *(half8*)&lo[c*8];
  }

  // b: LDS transpose -> bTh[v][jloc] rows (stride 72 halves)
  const float4* bp = (const float4*)(b + (size_t)j * DV);
  #pragma unroll
  for (int c = 0; c < 4; ++c) {
    float4 v = bp[c];
    sbt[tid][c*4+0] = (_Float16)v.x; sbt[tid][c*4+1] = (_Float16)v.y;
    sbt[tid][c*4+2] = (_Float16)v.z; sbt[tid][c*4+3] = (_Float16)v.w;
  }
  __syncthreads();
  #pragma unroll
  for (int r = 0; r < 2; ++r) {
    int cch = r * 256 + tid;                 // 512 chunks of 16B (4 tiles/block)
    int t4 = cch >> 7, rem = cch & 127, v = rem >> 3, jg = rem & 7;
    _Float16 tmp[8];
    #pragma unroll
    for (int k = 0; k < 8; ++k) tmp[k] = sbt[t4*64 + jg*8 + k][v];
    *(half8*)(rec0 + (size_t)(blockIdx.x*4 + t4)*REC + BT_OFF + v*144 + jg*16) =
        *(half8*)tmp;
  }

  // zero d_out (fused memset): 64 blocks x 256 threads x 4 float4 = 1 MB
  float4 z = {0.f, 0.f, 0.f, 0.f};
  float4* ozp = (float4*)outz;
  #pragma unroll
  for (int r = 0; r < 4; ++r) ozp[blockIdx.x * 1024 + r * 256 + tid] = z;
}

// ---------------- main MFMA kernel ----------------
__global__ __launch_bounds__(256, 4) void rbf_mfma(
    const float* __restrict__ ls, const float* __restrict__ x,
    const char* __restrict__ rec0, float* __restrict__ out) {
  __shared__ __align__(16) char SB[2][REC];            // 25600 B
  __shared__ __align__(16) _Float16 P[4][16 * PTS];    // 9216 B

  const int tid  = threadIdx.x;
  const int lane = tid & 63, w = tid >> 6;
  const int t = lane & 15, q = lane >> 4;
  const int iblk = blockIdx.x & 63, jseg = blockIdx.x >> 6;
  const int tseg = jseg * TILES;

  const float nl2g = -ls[0] * 1.4426950408889634f;
  const float m2g  = -2.0f * nl2g;            // positive; xs = m2g * x

  // x fragments (4 per wave): xs = (-2*nl2g)*x split hi/lo; xn' = nl2g*xn+14
  half8 xh[4], xl[4];
  float xns[4];
  #pragma unroll
  for (int f = 0; f < 4; ++f) {
    const int row = iblk * IBLK + f * 64 + w * 16 + t;
    const float4* xp = (const float4*)(x + (size_t)row * D + q * 8);
    float4 a0 = xp[0], a1 = xp[1];
    float fv[8] = {a0.x,a0.y,a0.z,a0.w,a1.x,a1.y,a1.z,a1.w};
    float s = 0.f;
    #pragma unroll
    for (int k = 0; k < 8; ++k) {
      s = fmaf(fv[k], fv[k], s);
      float vv = m2g * fv[k];
      _Float16 h = (_Float16)vv;
      xh[f][k] = h;
      xl[f][k] = (_Float16)(vv - (float)h);
    }
    s += __shfl_xor(s, 16);
    s += __shfl_xor(s, 32);
    xns[f] = fmaf(nl2g, s, 14.0f);
  }

  float4_t acc[4] = {{0,0,0,0},{0,0,0,0},{0,0,0,0},{0,0,0,0}};
  _Float16* __restrict__ myP = &P[w][0];

  stage_tile(rec0 + (size_t)tseg * REC, &SB[0][0], tid);
  __syncthreads();

  for (int k = 0; k < TILES; ++k) {
    if (k + 1 < TILES)
      stage_tile(rec0 + (size_t)(tseg + k + 1) * REC, &SB[(k + 1) & 1][0], tid);

    const char* rec = &SB[k & 1][0];
    const float* ynp = (const float*)rec;
    const char* yhp = rec + YH_OFF;
    const char* ylp = rec + YL_OFF;
    const _Float16* btp = (const _Float16*)(rec + BT_OFF);

    // per-tile y fragments, yn' vec, bT rows: read once, reuse over 4 frags
    half8 ah[4], al[4];
    float4_t yn4[4];
    #pragma unroll
    for (int s = 0; s < 4; ++s) {
      ah[s]  = *(const half8*)(yhp + (s * 16 + t) * 80 + q * 16);
      al[s]  = *(const half8*)(ylp + (s * 16 + t) * 80 + q * 16);
      yn4[s] = *(const float4_t*)(ynp + s * 16 + q * 4);
    }
    const half8 bh0 = *(const half8*)(btp + t * PTS + q * 8);
    const half8 bh1 = *(const half8*)(btp + t * PTS + 32 + q * 8);

    #pragma unroll
    for (int f = 0; f < 4; ++f) {
      #pragma unroll
      for (int s = 0; s < 4; ++s) {
        // c = nl2g*(xn+yn) + 14 + nl2g*(-2 x.y)  (3-MFMA hi/lo split)
        float4_t c = {yn4[s][0] + xns[f], yn4[s][1] + xns[f],
                      yn4[s][2] + xns[f], yn4[s][3] + xns[f]};
        c = __builtin_amdgcn_mfma_f32_16x16x32_f16(ah[s], xh[f], c, 0, 0, 0);
        c = __builtin_amdgcn_mfma_f32_16x16x32_f16(ah[s], xl[f], c, 0, 0, 0);
        c = __builtin_amdgcn_mfma_f32_16x16x32_f16(al[s], xh[f], c, 0, 0, 0);
        union { half4_t h4; cvt2_t c2[2]; } u;
        u.c2[0] = __builtin_amdgcn_cvt_pkrtz(exp2f(c[0]), exp2f(c[1]));
        u.c2[1] = __builtin_amdgcn_cvt_pkrtz(exp2f(c[2]), exp2f(c[3]));
        *(half4_t*)&myP[t * PTS + s * 16 + q * 4] = u.h4;
      }
      // same-wave DS RAW: order P writes before P reads
      __asm__ volatile("s_waitcnt lgkmcnt(0)" ::: "memory");
      const half8 pt0 = *(const half8*)&myP[t * PTS + q * 8];
      const half8 pt1 = *(const half8*)&myP[t * PTS + 32 + q * 8];
      acc[f] = __builtin_amdgcn_mfma_f32_16x16x32_f16(bh0, pt0, acc[f], 0, 0, 0);
      acc[f] = __builtin_amdgcn_mfma_f32_16x16x32_f16(bh1, pt1, acc[f], 0, 0, 0);
    }
    __syncthreads();   // drains staging vmcnt; protects SB double buffer
  }

  const float sc = 0.00006103515625f;  // 2^-14
  #pragma unroll
  for (int f = 0; f < 4; ++f) {
    float* orow = out + (size_t)(iblk * IBLK + f * 64 + w * 16 + t) * DV + q * 4;
    #pragma unroll
    for (int r = 0; r < 4; ++r) atomicAdd(&orow[r], acc[f][r] * sc);
  }
}

// ---------------- fallback (round-0 fp32 kernel, no ws) ----------------
#define BJ     128
#define BLOCK  256
#define FJSPLIT 32
#define SYP    36

__global__ __launch_bounds__(BLOCK) void rbf_fp32_kernel(
    const float* __restrict__ ls, const float* __restrict__ x,
    const float* __restrict__ y, const float* __restrict__ b,
    float* __restrict__ out, int N, int M) {
  __shared__ float sy[BJ * SYP];
  __shared__ float sb[BJ * DV];
  __shared__ float syn[BJ];
  const int itiles = N / BLOCK;
  const int itile  = blockIdx.x & (itiles - 1);
  const int jseg   = blockIdx.x / itiles;
  const int i      = itile * BLOCK + threadIdx.x;
  const int jlen   = M / FJSPLIT;
  const int j0     = jseg * jlen;
  const float g    = ls[0];
  const float nl2g = -g * 1.4426950408889634f;
  float xr[D]; float xn = 0.f;
  {
    const float4* xp = (const float4*)(x + (size_t)i * D);
    #pragma unroll
    for (int qq = 0; qq < D / 4; ++qq) {
      float4 v = xp[qq];
      xr[4*qq+0]=v.x; xr[4*qq+1]=v.y; xr[4*qq+2]=v.z; xr[4*qq+3]=v.w;
      xn += v.x*v.x + v.y*v.y + v.z*v.z + v.w*v.w;
    }
  }
  float acc[DV];
  #pragma unroll
  for (int v = 0; v < DV; ++v) acc[v] = 0.f;
  for (int jt = j0; jt < j0 + jlen; jt += BJ) {
    {
      const float4* src = (const float4*)(y + (size_t)jt * D);
      #pragma unroll
      for (int r = 0; r < (BJ * D / 4) / BLOCK; ++r) {
        int e4 = r * BLOCK + threadIdx.x;
        int j  = e4 >> 3; int dq = e4 & 7;
        *(float4*)&sy[j * SYP + dq * 4] = src[e4];
      }
      const float4* bsrc = (const float4*)(b + (size_t)jt * DV);
      #pragma unroll
      for (int r = 0; r < (BJ * DV / 4) / BLOCK; ++r) {
        int e4 = r * BLOCK + threadIdx.x;
        *(float4*)&sb[e4 * 4] = bsrc[e4];
      }
    }
    __syncthreads();
    if (threadIdx.x < BJ) {
      const float* row = &sy[threadIdx.x * SYP];
      float s0=0,s1=0,s2=0,s3=0;
      #pragma unroll
      for (int d = 0; d < D; d += 4) {
        s0=fmaf(row[d+0],row[d+0],s0); s1=fmaf(row[d+1],row[d+1],s1);
        s2=fmaf(row[d+2],row[d+2],s2); s3=fmaf(row[d+3],row[d+3],s3);
      }
      syn[threadIdx.x] = (s0+s1)+(s2+s3);
    }
    __syncthreads();
    #pragma unroll 2
    for (int j = 0; j < BJ; ++j) {
      const float* yrow = &sy[j * SYP];
      float d0=0,d1=0,d2=0,d3=0;
      #pragma unroll
      for (int d = 0; d < D; d += 4) {
        d0=fmaf(xr[d+0],yrow[d+0],d0); d1=fmaf(xr[d+1],yrow[d+1],d1);
        d2=fmaf(xr[d+2],yrow[d+2],d2); d3=fmaf(xr[d+3],yrow[d+3],d3);
      }
      float dot=(d0+d1)+(d2+d3);
      float sq = fmaxf(xn + syn[j] - 2.0f*dot, 0.0f);
      float p  = exp2f(nl2g * sq);
      const float* brow = &sb[j * DV];
      #pragma unroll
      for (int v = 0; v < DV; ++v) acc[v] = fmaf(p, brow[v], acc[v]);
    }
    __syncthreads();
  }
  float* orow = out + (size_t)i * DV;
  #pragma unroll
  for (int v = 0; v < DV; ++v) atomicAdd(&orow[v], acc[v]);
}

extern "C" void kernel_launch(void* const* d_in, const int* in_sizes, int n_in,
                              void* d_out, int out_size, void* d_ws, size_t ws_size,
                              hipStream_t stream) {
  const float* ls = (const float*)d_in[0];
  const float* x  = (const float*)d_in[1];
  const float* y  = (const float*)d_in[2];
  const float* b  = (const float*)d_in[3];
  float* out = (float*)d_out;

  const size_t need = (size_t)NTILE * REC;   // 3,276,800 B

  if (ws_size >= need) {
    char* rec0 = (char*)d_ws;
    rbf_prologue<<<NPTS / 256, 256, 0, stream>>>(ls, y, b, rec0, out);
    dim3 grid((NPTS / IBLK) * JSPLIT);       // 64 * 16 = 1024
    rbf_mfma<<<grid, 256, 0, stream>>>(ls, x, rec0, out);
  } else {
    (void)hipMemsetAsync(d_out, 0, (size_t)out_size * sizeof(float), stream);
    dim3 grid((NPTS / BLOCK) * FJSPLIT);
    rbf_fp32_kernel<<<grid, BLOCK, 0, stream>>>(ls, x, y, b, out, NPTS, NPTS);
  }
}

// Round 6
// 180.792 us; speedup vs baseline: 3.7028x; 1.0179x over previous
//
#include <hip/hip_runtime.h>

// out[i,v] = sum_j exp(-g*max(xn_i + yn_j - 2 x_i.y_j, 0)) * b[j,v]
// N=M=16384, D=32, Dv=16, fp32.
//
// Round 6: r5 structure with two changes:
//  (a) removed the per-f `s_waitcnt lgkmcnt(0)` + "memory" asm drain — the
//      same-wave P write->read is ordered by IR MayAlias + in-order DS pipe;
//  (b) amdgpu_waves_per_eu(4,4) pins occupancy so regalloc uses ~128 VGPRs
//      and keeps ah/al/yn4/bT resident across the f-loop (r5's VGPR=64
//      forced LDS re-reads every f).
// Record per 64-j tile: [yn' 256B | yh 64x80B | yl 64x80B | bTh 16x144B] = 12800 B.

#define NPTS 16384
#define D    32
#define DV   16
#define IBLK 256
#define JSPLIT 16
#define JBLK 64
#define NTILE  (NPTS / JBLK)        // 256
#define TILES  (NTILE / JSPLIT)     // 16 per block
#define REC    12800
#define YH_OFF 256
#define YL_OFF 5376
#define BT_OFF 10496
#define PTS    72                   // P row stride in halves

typedef _Float16 half8   __attribute__((ext_vector_type(8)));
typedef _Float16 half4_t __attribute__((ext_vector_type(4)));
typedef __fp16   cvt2_t  __attribute__((ext_vector_type(2)));
typedef float    float4_t __attribute__((ext_vector_type(4)));
typedef unsigned int u32;

__device__ __forceinline__ void async16(const void* g, void* l) {
  __builtin_amdgcn_global_load_lds((const __attribute__((address_space(1))) u32*)g,
                                   (__attribute__((address_space(3))) u32*)l, 16, 0, 0);
}

__device__ __forceinline__ void stage_tile(const char* __restrict__ g,
                                           char* __restrict__ l, int tid) {
  async16(g + tid * 16,         l + tid * 16);
  async16(g + 4096 + tid * 16,  l + 4096 + tid * 16);
  async16(g + 8192 + tid * 16,  l + 8192 + tid * 16);
  if (tid < 32) async16(g + 12288 + tid * 16, l + 12288 + tid * 16);
}

// ---------------- prologue: records (yn' scaled, yh, yl, bTh) + out zero ----
__global__ __launch_bounds__(256) void rbf_prologue(
    const float* __restrict__ ls, const float* __restrict__ y,
    const float* __restrict__ b, char* __restrict__ rec0,
    float* __restrict__ outz) {
  __shared__ _Float16 sbt[256][17];
  const int tid = threadIdx.x;
  const int j = blockIdx.x * 256 + tid;
  const int tt = j >> 6, jloc = j & 63;
  char* rec = rec0 + (size_t)tt * REC;
  const float nl2g = -ls[0] * 1.4426950408889634f;

  // y row: scaled yn' + plain hi/lo split
  const float4* yp = (const float4*)(y + (size_t)j * D);
  float s = 0.f;
  _Float16 hi[32], lo[32];
  #pragma unroll
  for (int c = 0; c < 8; ++c) {
    float4 v = yp[c];
    float f[4] = {v.x, v.y, v.z, v.w};
    #pragma unroll
    for (int k = 0; k < 4; ++k) {
      s = fmaf(f[k], f[k], s);
      _Float16 h = (_Float16)f[k];
      hi[c*4+k] = h;
      lo[c*4+k] = (_Float16)(f[k] - (float)h);
    }
  }
  ((float*)rec)[jloc] = nl2g * s;
  #pragma unroll
  for (int c = 0; c < 4; ++c) {
    *(half8*)(rec + YH_OFF + jloc * 80 + c * 16) = *(half8*)&hi[c*8];
    *(half8*)(rec + YL_OFF + jloc * 80 + c * 16) = *(half8*)&lo[c*8];
  }

  // b: LDS transpose -> bTh[v][jloc] rows (stride 72 halves)
  const float4* bp = (const float4*)(b + (size_t)j * DV);
  #pragma unroll
  for (int c = 0; c < 4; ++c) {
    float4 v = bp[c];
    sbt[tid][c*4+0] = (_Float16)v.x; sbt[tid][c*4+1] = (_Float16)v.y;
    sbt[tid][c*4+2] = (_Float16)v.z; sbt[tid][c*4+3] = (_Float16)v.w;
  }
  __syncthreads();
  #pragma unroll
  for (int r = 0; r < 2; ++r) {
    int cch = r * 256 + tid;                 // 512 chunks of 16B (4 tiles/block)
    int t4 = cch >> 7, rem = cch & 127, v = rem >> 3, jg = rem & 7;
    _Float16 tmp[8];
    #pragma unroll
    for (int k = 0; k < 8; ++k) tmp[k] = sbt[t4*64 + jg*8 + k][v];
    *(half8*)(rec0 + (size_t)(blockIdx.x*4 + t4)*REC + BT_OFF + v*144 + jg*16) =
        *(half8*)tmp;
  }

  // zero d_out (fused memset): 64 blocks x 256 threads x 4 float4 = 1 MB
  float4 z = {0.f, 0.f, 0.f, 0.f};
  float4* ozp = (float4*)outz;
  #pragma unroll
  for (int r = 0; r < 4; ++r) ozp[blockIdx.x * 1024 + r * 256 + tid] = z;
}

// ---------------- main MFMA kernel ----------------
__global__ __launch_bounds__(256)
__attribute__((amdgpu_waves_per_eu(4, 4)))
void rbf_mfma(
    const float* __restrict__ ls, const float* __restrict__ x,
    const char* __restrict__ rec0, float* __restrict__ out) {
  __shared__ __align__(16) char SB[2][REC];            // 25600 B
  __shared__ __align__(16) _Float16 P[4][16 * PTS];    // 9216 B

  const int tid  = threadIdx.x;
  const int lane = tid & 63, w = tid >> 6;
  const int t = lane & 15, q = lane >> 4;
  const int iblk = blockIdx.x & 63, jseg = blockIdx.x >> 6;
  const int tseg = jseg * TILES;

  const float nl2g = -ls[0] * 1.4426950408889634f;
  const float m2g  = -2.0f * nl2g;            // positive; xs = m2g * x

  // x fragments (4 per wave): xs = (-2*nl2g)*x split hi/lo; xn' = nl2g*xn+14
  half8 xh[4], xl[4];
  float xns[4];
  #pragma unroll
  for (int f = 0; f < 4; ++f) {
    const int row = iblk * IBLK + f * 64 + w * 16 + t;
    const float4* xp = (const float4*)(x + (size_t)row * D + q * 8);
    float4 a0 = xp[0], a1 = xp[1];
    float fv[8] = {a0.x,a0.y,a0.z,a0.w,a1.x,a1.y,a1.z,a1.w};
    float s = 0.f;
    #pragma unroll
    for (int k = 0; k < 8; ++k) {
      s = fmaf(fv[k], fv[k], s);
      float vv = m2g * fv[k];
      _Float16 h = (_Float16)vv;
      xh[f][k] = h;
      xl[f][k] = (_Float16)(vv - (float)h);
    }
    s += __shfl_xor(s, 16);
    s += __shfl_xor(s, 32);
    xns[f] = fmaf(nl2g, s, 14.0f);
  }

  float4_t acc[4] = {{0,0,0,0},{0,0,0,0},{0,0,0,0},{0,0,0,0}};
  _Float16* __restrict__ myP = &P[w][0];

  stage_tile(rec0 + (size_t)tseg * REC, &SB[0][0], tid);
  __syncthreads();

  for (int k = 0; k < TILES; ++k) {
    if (k + 1 < TILES)
      stage_tile(rec0 + (size_t)(tseg + k + 1) * REC, &SB[(k + 1) & 1][0], tid);

    const char* rec = &SB[k & 1][0];
    const float* ynp = (const float*)rec;
    const char* yhp = rec + YH_OFF;
    const char* ylp = rec + YL_OFF;
    const _Float16* btp = (const _Float16*)(rec + BT_OFF);

    // per-tile y fragments, yn' vec, bT rows: read once, reuse over 4 frags
    half8 ah[4], al[4];
    float4_t yn4[4];
    #pragma unroll
    for (int s = 0; s < 4; ++s) {
      ah[s]  = *(const half8*)(yhp + (s * 16 + t) * 80 + q * 16);
      al[s]  = *(const half8*)(ylp + (s * 16 + t) * 80 + q * 16);
      yn4[s] = *(const float4_t*)(ynp + s * 16 + q * 4);
    }
    const half8 bh0 = *(const half8*)(btp + t * PTS + q * 8);
    const half8 bh1 = *(const half8*)(btp + t * PTS + 32 + q * 8);

    #pragma unroll
    for (int f = 0; f < 4; ++f) {
      #pragma unroll
      for (int s = 0; s < 4; ++s) {
        // c = nl2g*(xn+yn) + 14 + nl2g*(-2 x.y)  (3-MFMA hi/lo split)
        float4_t c = {yn4[s][0] + xns[f], yn4[s][1] + xns[f],
                      yn4[s][2] + xns[f], yn4[s][3] + xns[f]};
        c = __builtin_amdgcn_mfma_f32_16x16x32_f16(ah[s], xh[f], c, 0, 0, 0);
        c = __builtin_amdgcn_mfma_f32_16x16x32_f16(ah[s], xl[f], c, 0, 0, 0);
        c = __builtin_amdgcn_mfma_f32_16x16x32_f16(al[s], xh[f], c, 0, 0, 0);
        union { half4_t h4; cvt2_t c2[2]; } u;
        u.c2[0] = __builtin_amdgcn_cvt_pkrtz(exp2f(c[0]), exp2f(c[1]));
        u.c2[1] = __builtin_amdgcn_cvt_pkrtz(exp2f(c[2]), exp2f(c[3]));
        *(half4_t*)&myP[t * PTS + s * 16 + q * 4] = u.h4;
      }
      // Same-wave P write->read: ordered by MayAlias (program order kept) +
      // in-order per-wave DS pipe. No explicit drain — lets f-chains overlap.
      const half8 pt0 = *(const half8*)&myP[t * PTS + q * 8];
      const half8 pt1 = *(const half8*)&myP[t * PTS + 32 + q * 8];
      acc[f] = __builtin_amdgcn_mfma_f32_16x16x32_f16(bh0, pt0, acc[f], 0, 0, 0);
      acc[f] = __builtin_amdgcn_mfma_f32_16x16x32_f16(bh1, pt1, acc[f], 0, 0, 0);
    }
    __syncthreads();   // drains staging vmcnt; protects SB double buffer
  }

  const float sc = 0.00006103515625f;  // 2^-14
  #pragma unroll
  for (int f = 0; f < 4; ++f) {
    float* orow = out + (size_t)(iblk * IBLK + f * 64 + w * 16 + t) * DV + q * 4;
    #pragma unroll
    for (int r = 0; r < 4; ++r) atomicAdd(&orow[r], acc[f][r] * sc);
  }
}

// ---------------- fallback (round-0 fp32 kernel, no ws) ----------------
#define BJ     128
#define BLOCK  256
#define FJSPLIT 32
#define SYP    36

__global__ __launch_bounds__(BLOCK) void rbf_fp32_kernel(
    const float* __restrict__ ls, const float* __restrict__ x,
    const float* __restrict__ y, const float* __restrict__ b,
    float* __restrict__ out, int N, int M) {
  __shared__ float sy[BJ * SYP];
  __shared__ float sb[BJ * DV];
  __shared__ float syn[BJ];
  const int itiles = N / BLOCK;
  const int itile  = blockIdx.x & (itiles - 1);
  const int jseg   = blockIdx.x / itiles;
  const int i      = itile * BLOCK + threadIdx.x;
  const int jlen   = M / FJSPLIT;
  const int j0     = jseg * jlen;
  const float g    = ls[0];
  const float nl2g = -g * 1.4426950408889634f;
  float xr[D]; float xn = 0.f;
  {
    const float4* xp = (const float4*)(x + (size_t)i * D);
    #pragma unroll
    for (int qq = 0; qq < D / 4; ++qq) {
      float4 v = xp[qq];
      xr[4*qq+0]=v.x; xr[4*qq+1]=v.y; xr[4*qq+2]=v.z; xr[4*qq+3]=v.w;
      xn += v.x*v.x + v.y*v.y + v.z*v.z + v.w*v.w;
    }
  }
  float acc[DV];
  #pragma unroll
  for (int v = 0; v < DV; ++v) acc[v] = 0.f;
  for (int jt = j0; jt < j0 + jlen; jt += BJ) {
    {
      const float4* src = (const float4*)(y + (size_t)jt * D);
      #pragma unroll
      for (int r = 0; r < (BJ * D / 4) / BLOCK; ++r) {
        int e4 = r * BLOCK + threadIdx.x;
        int j  = e4 >> 3; int dq = e4 & 7;
        *(float4*)&sy[j * SYP + dq * 4] = src[e4];
      }
      const float4* bsrc = (const float4*)(b + (size_t)jt * DV);
      #pragma unroll
      for (int r = 0; r < (BJ * DV / 4) / BLOCK; ++r) {
        int e4 = r * BLOCK + threadIdx.x;
        *(float4*)&sb[e4 * 4] = bsrc[e4];
      }
    }
    __syncthreads();
    if (threadIdx.x < BJ) {
      const float* row = &sy[threadIdx.x * SYP];
      float s0=0,s1=0,s2=0,s3=0;
      #pragma unroll
      for (int d = 0; d < D; d += 4) {
        s0=fmaf(row[d+0],row[d+0],s0); s1=fmaf(row[d+1],row[d+1],s1);
        s2=fmaf(row[d+2],row[d+2],s2); s3=fmaf(row[d+3],row[d+3],s3);
      }
      syn[threadIdx.x] = (s0+s1)+(s2+s3);
    }
    __syncthreads();
    #pragma unroll 2
    for (int j = 0; j < BJ; ++j) {
      const float* yrow = &sy[j * SYP];
      float d0=0,d1=0,d2=0,d3=0;
      #pragma unroll
      for (int d = 0; d < D; d += 4) {
        d0=fmaf(xr[d+0],yrow[d+0],d0); d1=fmaf(xr[d+1],yrow[d+1],d1);
        d2=fmaf(xr[d+2],yrow[d+2],d2); d3=fmaf(xr[d+3],yrow[d+3],d3);
      }
      float dot=(d0+d1)+(d2+d3);
      float sq = fmaxf(xn + syn[j] - 2.0f*dot, 0.0f);
      float p  = exp2f(nl2g * sq);
      const float* brow = &sb[j * DV];
      #pragma unroll
      for (int v = 0; v < DV; ++v) acc[v] = fmaf(p, brow[v], acc[v]);
    }
    __syncthreads();
  }
  float* orow = out + (size_t)i * DV;
  #pragma unroll
  for (int v = 0; v < DV; ++v) atomicAdd(&orow[v], acc[v]);
}

extern "C" void kernel_launch(void* const* d_in, const int* in_sizes, int n_in,
                              void* d_out, int out_size, void* d_ws, size_t ws_size,
                              hipStream_t stream) {
  const float* ls = (const float*)d_in[0];
  const float* x  = (const float*)d_in[1];
  const float* y  = (const float*)d_in[2];
  const float* b  = (const float*)d_in[3];
  float* out = (float*)d_out;

  const size_t need = (size_t)NTILE * REC;   // 3,276,800 B

  if (ws_size >= need) {
    char* rec0 = (char*)d_ws;
    rbf_prologue<<<NPTS / 256, 256, 0, stream>>>(ls, y, b, rec0, out);
    dim3 grid((NPTS / IBLK) * JSPLIT);       // 64 * 16 = 1024
    rbf_mfma<<<grid, 256, 0, stream>>>(ls, x, rec0, out);
  } else {
    (void)hipMemsetAsync(d_out, 0, (size_t)out_size * sizeof(float), stream);
    dim3 grid((NPTS / BLOCK) * FJSPLIT);
    rbf_fp32_kernel<<<grid, BLOCK, 0, stream>>>(ls, x, y, b, out, NPTS, NPTS);
  }
}